// Round 1
// baseline (134.381 us; speedup 1.0000x reference)
//
#include <hip/hip_runtime.h>

// VQ-VAE vector quantizer, MI355X.
// z_e: [32,64,32,32] f32, codebook: [1024,64] f32.
// d_out = q_out(2097152) | loss(1) | perplexity(1) | encodings(33554432), all f32.
//
// ws layout (4-byte units):
//   [0,1024)       hist (int)          -- zeroed via memsetAsync each call
//   [1024,2048)    ensq (float)        -- codebook squared norms
//   [2048,34816)   idx  (int[32768])
//   [34816,35328)  partials (float[512]) -- per-block loss partial sums
// total 141312 bytes of ws used.

#define NROWS 32768
#define KC    1024
#define DD    64
#define HW    1024
#define CHW   65536

__global__ __launch_bounds__(256) void vq_ensq_kernel(const float* __restrict__ cb,
                                                      float* __restrict__ ensq) {
  int k = blockIdx.x * 256 + threadIdx.x;
  const float* row = cb + k * DD;
  float s = 0.f;
#pragma unroll
  for (int c = 0; c < DD; ++c) s = fmaf(row[c], row[c], s);
  ensq[k] = s;
}

__global__ __launch_bounds__(256) void vq_argmin_kernel(
    const float* __restrict__ z_e, const float* __restrict__ cb,
    const float* __restrict__ ensq_g, float* __restrict__ qout,
    int* __restrict__ idx_out, int* __restrict__ hist,
    float* __restrict__ partials) {
  __shared__ float lds_cb[256 * DD];   // 64 KB codebook tile (256 codes)
  __shared__ float lds_ensq[KC];       // 4 KB
  __shared__ float s_val[4][64];
  __shared__ int   s_idx[4][64];
  __shared__ float s_loss[4];

  const int tid  = threadIdx.x;
  const int lane = tid & 63;
  const int wave = __builtin_amdgcn_readfirstlane(tid >> 6);  // force uniform
  const int n    = blockIdx.x * 64 + lane;
  const int b    = n >> 10;
  const int hw   = n & (HW - 1);
  const float* zp = z_e + (size_t)b * CHW + hw;

  // stage codebook norms into LDS (visibility covered by first tile barrier)
  {
    float4* d4 = (float4*)lds_ensq;
    const float4* s4 = (const float4*)ensq_g;
    d4[tid] = s4[tid];
  }

  // this thread's z vector: 64 VGPRs, coalesced loads (lanes = consecutive hw)
  float z[DD];
#pragma unroll
  for (int c = 0; c < DD; ++c) z[c] = zp[(size_t)c << 10];

  float zsq = 0.f;
#pragma unroll
  for (int c = 0; c < DD; ++c) zsq = fmaf(z[c], z[c], zsq);

  float bestd = 3.402823466e38f;
  int   besti = 0;

  for (int tile = 0; tile < 4; ++tile) {
    __syncthreads();
    {
      const float4* src = (const float4*)(cb + (size_t)tile * 256 * DD);
      float4* dst = (float4*)lds_cb;
#pragma unroll
      for (int i = 0; i < 16; ++i) dst[tid + 256 * i] = src[tid + 256 * i];
    }
    __syncthreads();

    const int kb = wave * 64;  // this wave's 64-code slice of the tile
    for (int kk = 0; kk < 64; kk += 4) {
      const float* p = &lds_cb[(kb + kk) * DD];
      float s0 = 0.f, s1 = 0.f, s2 = 0.f, s3 = 0.f;
#pragma unroll
      for (int c = 0; c < DD; ++c) {
        float zc = z[c];
        s0 = fmaf(zc, p[c         ], s0);
        s1 = fmaf(zc, p[c +     DD], s1);
        s2 = fmaf(zc, p[c + 2 * DD], s2);
        s3 = fmaf(zc, p[c + 3 * DD], s3);
      }
      const int kg = tile * 256 + kb + kk;
      // mimic ref rounding: (||z||^2 + ||e||^2) - 2*(z.e), all fp32
      float d0 = (zsq + lds_ensq[kg + 0]) - 2.f * s0;
      float d1 = (zsq + lds_ensq[kg + 1]) - 2.f * s1;
      float d2 = (zsq + lds_ensq[kg + 2]) - 2.f * s2;
      float d3 = (zsq + lds_ensq[kg + 3]) - 2.f * s3;
      if (d0 < bestd) { bestd = d0; besti = kg + 0; }
      if (d1 < bestd) { bestd = d1; besti = kg + 1; }
      if (d2 < bestd) { bestd = d2; besti = kg + 2; }
      if (d3 < bestd) { bestd = d3; besti = kg + 3; }
    }
  }

  s_val[wave][lane] = bestd;
  s_idx[wave][lane] = besti;
  __syncthreads();

  // cross-wave argmin reduce (first-min tie-break on index), by wave 0
  if (wave == 0) {
    float bd = s_val[0][lane];
    int   bi = s_idx[0][lane];
#pragma unroll
    for (int w2 = 1; w2 < 4; ++w2) {
      float d  = s_val[w2][lane];
      int   i2 = s_idx[w2][lane];
      if (d < bd || (d == bd && i2 < bi)) { bd = d; bi = i2; }
    }
    s_idx[0][lane] = bi;   // broadcast final index
    idx_out[n] = bi;
    atomicAdd(&hist[bi], 1);
  }
  __syncthreads();

  // fused epilogue: q_out write + loss partial. Each wave handles 16 channels
  // for all 64 rows of the block. Reload z from global (L1/L2-hot) to avoid
  // runtime-indexing the z[] register array (scratch spill, rule #20).
  const int bif = s_idx[0][lane];
  const float* cbrow = cb + (size_t)bif * DD;
  float* qp = qout + (size_t)b * CHW + hw;
  float lacc = 0.f;
#pragma unroll
  for (int j = 0; j < 16; ++j) {
    int c = wave * 16 + j;
    float v    = cbrow[c];
    float zc   = zp[(size_t)c << 10];
    float diff = v - zc;               // matches ref (quantized - ze)
    qp[(size_t)c << 10] = zc + diff;   // matches ref ze + (quantized - ze)
    lacc = fmaf(diff, diff, lacc);
  }
#pragma unroll
  for (int off = 32; off > 0; off >>= 1) lacc += __shfl_down(lacc, off, 64);
  if (lane == 0) s_loss[wave] = lacc;
  __syncthreads();
  if (tid == 0) partials[blockIdx.x] = s_loss[0] + s_loss[1] + s_loss[2] + s_loss[3];
}

// one wave per row: write full one-hot row (zeros + single 1.0) at stream BW.
// float2 stores because the encodings base (float offset 2097154) is only
// 8-byte aligned.
__global__ __launch_bounds__(256) void vq_encodings_kernel(
    const int* __restrict__ idx, float* __restrict__ enc) {
  const int tid  = threadIdx.x;
  const int lane = tid & 63;
  const int wave = tid >> 6;
  const int row  = blockIdx.x * 4 + wave;
  const int bi   = idx[row];
  float2* out = (float2*)(enc + (size_t)row * KC);
#pragma unroll
  for (int j = 0; j < 8; ++j) {
    int f2   = lane + 64 * j;     // 0..511
    int base = f2 * 2;
    float2 v;
    v.x = (base     == bi) ? 1.f : 0.f;
    v.y = (base + 1 == bi) ? 1.f : 0.f;
    out[f2] = v;
  }
}

__global__ __launch_bounds__(1024) void vq_finalize_kernel(
    const int* __restrict__ hist, const float* __restrict__ partials,
    float* __restrict__ out_loss, float* __restrict__ out_ppl) {
  __shared__ float red[1024];
  const int t = threadIdx.x;

  // entropy term
  float p   = (float)hist[t] * (1.0f / 32768.0f);
  float ent = p * logf(p + 1e-10f);
  red[t] = ent;
  __syncthreads();
  for (int s = 512; s > 0; s >>= 1) {
    if (t < s) red[t] += red[t + s];
    __syncthreads();
  }
  float entropy = red[0];
  __syncthreads();

  // loss sum
  red[t] = (t < 512) ? partials[t] : 0.f;
  __syncthreads();
  for (int s = 512; s > 0; s >>= 1) {
    if (t < s) red[t] += red[t + s];
    __syncthreads();
  }
  if (t == 0) {
    *out_loss = 0.25f * (red[0] * (1.0f / 2097152.0f));
    *out_ppl  = expf(-entropy);
  }
}

extern "C" void kernel_launch(void* const* d_in, const int* in_sizes, int n_in,
                              void* d_out, int out_size, void* d_ws, size_t ws_size,
                              hipStream_t stream) {
  const float* z_e = (const float*)d_in[0];
  const float* cb  = (const float*)d_in[1];

  float* out  = (float*)d_out;
  float* qout = out;                       // 2097152
  float* loss = out + 2097152;
  float* ppl  = out + 2097153;
  float* enc  = out + 2097154;             // 33554432 floats

  int*   hist     = (int*)d_ws;
  float* ensq     = (float*)d_ws + 1024;
  int*   idx      = (int*)d_ws + 2048;
  float* partials = (float*)d_ws + 34816;

  hipMemsetAsync(hist, 0, KC * sizeof(int), stream);
  vq_ensq_kernel<<<4, 256, 0, stream>>>(cb, ensq);
  vq_argmin_kernel<<<512, 256, 0, stream>>>(z_e, cb, ensq, qout, idx, hist, partials);
  vq_encodings_kernel<<<NROWS / 4, 256, 0, stream>>>(idx, enc);
  vq_finalize_kernel<<<1, 1024, 0, stream>>>(hist, partials, loss, ppl);
}

// Round 3
// 129.999 us; speedup vs baseline: 1.0337x; 1.0337x over previous
//
#include <hip/hip_runtime.h>

// VQ-VAE vector quantizer, MI355X.
// z_e: [32,64,32,32] f32, codebook: [1024,64] f32.
// d_out = q_out(2097152) | loss(1) | perplexity(1) | encodings(33554432), all f32.
//
// ws layout (4-byte units):
//   [0,1024)       hist (int)            -- zeroed via memsetAsync each call
//   [1024,2048)    ensq (float)          -- codebook squared norms
//   [2048,34816)   idx  (int[32768])
//   [34816,35328)  partials (float[512]) -- per-block loss partial sums

#define NROWS 32768
#define KC    1024
#define DD    64
#define HW    1024
#define CHW   65536
#define WAVES 8           // 512 threads/block, 8-way K split (128 codes/wave)

typedef float f32x2 __attribute__((ext_vector_type(2)));

__global__ __launch_bounds__(256) void vq_ensq_kernel(const float* __restrict__ cb,
                                                      float* __restrict__ ensq) {
  int k = blockIdx.x * 256 + threadIdx.x;
  const float* row = cb + k * DD;
  float s = 0.f;
#pragma unroll
  for (int c = 0; c < DD; ++c) s = fmaf(row[c], row[c], s);
  ensq[k] = s;
}

__global__ __launch_bounds__(512, 4) void vq_argmin_kernel(
    const float* __restrict__ z_e, const float* __restrict__ cb,
    const float* __restrict__ ensq_g, float* __restrict__ qout,
    int* __restrict__ idx_out, int* __restrict__ hist,
    float* __restrict__ partials) {
  __shared__ float s_val[WAVES][64];
  __shared__ int   s_idx[WAVES][64];
  __shared__ float s_loss[WAVES];

  const int tid  = threadIdx.x;
  const int lane = tid & 63;
  const int wave = __builtin_amdgcn_readfirstlane(tid >> 6);  // wave-uniform
  const int n    = blockIdx.x * 64 + lane;
  const int b    = n >> 10;
  const int hw   = n & (HW - 1);
  const float* zp = z_e + (size_t)b * CHW + hw;

  // this thread's z vector: 64 VGPRs, coalesced loads (lanes = consecutive hw)
  float z[DD];
#pragma unroll
  for (int c = 0; c < DD; ++c) z[c] = zp[(size_t)c << 10];

  float zsq = 0.f;
#pragma unroll
  for (int c = 0; c < DD; ++c) zsq = fmaf(z[c], z[c], zsq);

  // This wave scans codes [kbase, kbase+128). All codebook/ensq addresses in
  // the loop are wave-uniform -> compiler emits scalar (s_load) or broadcast
  // vector loads; inner loop is pure VALU with 4 independent fmaf chains.
  const int kbase = wave * (KC / WAVES);
  float bestd = 3.402823466e38f;
  int   besti = 0;

  for (int kk = 0; kk < KC / WAVES; kk += 4) {
    const int kg = kbase + kk;
    const float* p = cb + (size_t)kg * DD;   // 4 consecutive code rows, 1 KB
    float s0 = 0.f, s1 = 0.f, s2 = 0.f, s3 = 0.f;
#pragma unroll
    for (int c = 0; c < DD; ++c) {
      float zc = z[c];
      s0 = fmaf(zc, p[c         ], s0);
      s1 = fmaf(zc, p[c +     DD], s1);
      s2 = fmaf(zc, p[c + 2 * DD], s2);
      s3 = fmaf(zc, p[c + 3 * DD], s3);
    }
    // mimic ref rounding: (||z||^2 + ||e||^2) - 2*(z.e), all fp32
    float d0 = (zsq + ensq_g[kg + 0]) - 2.f * s0;
    float d1 = (zsq + ensq_g[kg + 1]) - 2.f * s1;
    float d2 = (zsq + ensq_g[kg + 2]) - 2.f * s2;
    float d3 = (zsq + ensq_g[kg + 3]) - 2.f * s3;
    if (d0 < bestd) { bestd = d0; besti = kg + 0; }
    if (d1 < bestd) { bestd = d1; besti = kg + 1; }
    if (d2 < bestd) { bestd = d2; besti = kg + 2; }
    if (d3 < bestd) { bestd = d3; besti = kg + 3; }
  }

  s_val[wave][lane] = bestd;
  s_idx[wave][lane] = besti;
  __syncthreads();

  // cross-wave argmin reduce (first-min tie-break on lower index), by wave 0
  if (wave == 0) {
    float bd = s_val[0][lane];
    int   bi = s_idx[0][lane];
#pragma unroll
    for (int w2 = 1; w2 < WAVES; ++w2) {
      float d  = s_val[w2][lane];
      int   i2 = s_idx[w2][lane];
      if (d < bd || (d == bd && i2 < bi)) { bd = d; bi = i2; }
    }
    s_idx[0][lane] = bi;   // broadcast final index
    idx_out[n] = bi;
    atomicAdd(&hist[bi], 1);
  }
  __syncthreads();

  // fused epilogue: q_out write + loss partial. Each wave handles 8 channels
  // for all 64 rows of the block. Reload z from global (L1/L2-hot) to avoid
  // runtime-indexing the z[] register array (scratch spill, rule #20).
  const int bif = s_idx[0][lane];
  const float* cbrow = cb + (size_t)bif * DD;
  float* qp = qout + (size_t)b * CHW + hw;
  float lacc = 0.f;
#pragma unroll
  for (int j = 0; j < DD / WAVES; ++j) {
    int c = wave * (DD / WAVES) + j;
    float v    = cbrow[c];
    float zc   = zp[(size_t)c << 10];
    float diff = v - zc;               // matches ref (quantized - ze)
    qp[(size_t)c << 10] = zc + diff;   // matches ref ze + (quantized - ze)
    lacc = fmaf(diff, diff, lacc);
  }
#pragma unroll
  for (int off = 32; off > 0; off >>= 1) lacc += __shfl_down(lacc, off, 64);
  if (lane == 0) s_loss[wave] = lacc;
  __syncthreads();
  if (tid == 0) {
    float t = 0.f;
#pragma unroll
    for (int w2 = 0; w2 < WAVES; ++w2) t += s_loss[w2];
    partials[blockIdx.x] = t;
  }
}

// one wave per row: write full one-hot row (zeros + single 1.0) at stream BW.
// f32x2 stores because the encodings base (float offset 2097154) is only
// 8-byte aligned. Nontemporal: pure streaming writes, never re-read by us.
__global__ __launch_bounds__(256) void vq_encodings_kernel(
    const int* __restrict__ idx, float* __restrict__ enc) {
  const int tid  = threadIdx.x;
  const int lane = tid & 63;
  const int wave = tid >> 6;
  const int row  = blockIdx.x * 4 + wave;
  const int bi   = idx[row];
  f32x2* out = (f32x2*)(enc + (size_t)row * KC);
#pragma unroll
  for (int j = 0; j < 8; ++j) {
    int f2   = lane + 64 * j;     // 0..511
    int base = f2 * 2;
    f32x2 v;
    v.x = (base     == bi) ? 1.f : 0.f;
    v.y = (base + 1 == bi) ? 1.f : 0.f;
    __builtin_nontemporal_store(v, &out[f2]);
  }
}

__global__ __launch_bounds__(1024) void vq_finalize_kernel(
    const int* __restrict__ hist, const float* __restrict__ partials,
    float* __restrict__ out_loss, float* __restrict__ out_ppl) {
  __shared__ float red[1024];
  const int t = threadIdx.x;

  // entropy term
  float p   = (float)hist[t] * (1.0f / 32768.0f);
  float ent = p * logf(p + 1e-10f);
  red[t] = ent;
  __syncthreads();
  for (int s = 512; s > 0; s >>= 1) {
    if (t < s) red[t] += red[t + s];
    __syncthreads();
  }
  float entropy = red[0];
  __syncthreads();

  // loss sum
  red[t] = (t < 512) ? partials[t] : 0.f;
  __syncthreads();
  for (int s = 512; s > 0; s >>= 1) {
    if (t < s) red[t] += red[t + s];
    __syncthreads();
  }
  if (t == 0) {
    *out_loss = 0.25f * (red[0] * (1.0f / 2097152.0f));
    *out_ppl  = expf(-entropy);
  }
}

extern "C" void kernel_launch(void* const* d_in, const int* in_sizes, int n_in,
                              void* d_out, int out_size, void* d_ws, size_t ws_size,
                              hipStream_t stream) {
  const float* z_e = (const float*)d_in[0];
  const float* cb  = (const float*)d_in[1];

  float* out  = (float*)d_out;
  float* qout = out;                       // 2097152
  float* loss = out + 2097152;
  float* ppl  = out + 2097153;
  float* enc  = out + 2097154;             // 33554432 floats

  int*   hist     = (int*)d_ws;
  float* ensq     = (float*)d_ws + 1024;
  int*   idx      = (int*)d_ws + 2048;
  float* partials = (float*)d_ws + 34816;

  (void)hipMemsetAsync(hist, 0, KC * sizeof(int), stream);
  vq_ensq_kernel<<<4, 256, 0, stream>>>(cb, ensq);
  vq_argmin_kernel<<<512, 512, 0, stream>>>(z_e, cb, ensq, qout, idx, hist, partials);
  vq_encodings_kernel<<<NROWS / 4, 256, 0, stream>>>(idx, enc);
  vq_finalize_kernel<<<1, 1024, 0, stream>>>(hist, partials, loss, ppl);
}

// Round 4
// 105.161 us; speedup vs baseline: 1.2779x; 1.2362x over previous
//
#include <hip/hip_runtime.h>

// VQ-VAE vector quantizer, MI355X.
// z_e: [32,64,32,32] f32, codebook: [1024,64] f32.
// d_out = q_out(2097152) | loss(1) | perplexity(1) | encodings(33554432), all f32.
//
// Pipeline (3 dispatches):
//   1. vq_ensq_kernel    : codebook squared norms + hist zero (1024 threads)
//   2. vq_argmin_kernel  : fused distances+argmin+q_out+loss+hist+encodings
//   3. vq_finalize_kernel: loss mean + perplexity
//
// ws layout (4-byte units):
//   [0,1024)       hist (int)
//   [1024,2048)    ensq (float)
//   [34816,35328)  partials (float[512])

#define NROWS 32768
#define KC    1024
#define DD    64
#define HW    1024
#define CHW   65536
#define WAVES 8           // 512 threads/block, 8-way K split (128 codes/wave)

typedef float f32x2 __attribute__((ext_vector_type(2)));

__global__ __launch_bounds__(256) void vq_ensq_kernel(const float* __restrict__ cb,
                                                      float* __restrict__ ensq,
                                                      int* __restrict__ hist) {
  int k = blockIdx.x * 256 + threadIdx.x;   // 4 blocks x 256 = exactly KC
  hist[k] = 0;
  const float* row = cb + k * DD;
  float s = 0.f;
#pragma unroll
  for (int c = 0; c < DD; ++c) s = fmaf(row[c], row[c], s);
  ensq[k] = s;
}

__global__ __launch_bounds__(512, 2) void vq_argmin_kernel(
    const float* __restrict__ z_e, const float* __restrict__ cb,
    const float* __restrict__ ensq_g, float* __restrict__ qout,
    float* __restrict__ enc, int* __restrict__ hist,
    float* __restrict__ partials) {
  __shared__ float s_val[WAVES][64];
  __shared__ int   s_idx[WAVES][64];
  __shared__ float s_loss[WAVES];

  const int tid  = threadIdx.x;
  const int lane = tid & 63;
  const int wave = __builtin_amdgcn_readfirstlane(tid >> 6);  // wave-uniform
  const int n    = blockIdx.x * 64 + lane;
  const int b    = n >> 10;
  const int hw   = n & (HW - 1);
  const float* zp = z_e + (size_t)b * CHW + hw;

  // this thread's z vector: 64 VGPRs, coalesced loads (lanes = consecutive hw).
  // asm pin: makes each value an opaque asm result so the compiler CANNOT
  // rematerialize the loads inside the K-loop (round-3 pathology: VGPR=44,
  // z reloaded 32x from global).
  float z[DD];
#pragma unroll
  for (int c = 0; c < DD; ++c) {
    z[c] = zp[(size_t)c << 10];
    asm volatile("" : "+v"(z[c]));
  }

  float zsq = 0.f;
#pragma unroll
  for (int c = 0; c < DD; ++c) zsq = fmaf(z[c], z[c], zsq);

  // Streaming zero-fill of this block's encodings slice (64 rows x 1024 =
  // 256 KB), interleaved with the distance loop: 16 B/thread/K-group.
  // 8-byte stores because enc base (float offset 2097154) is 8B-aligned only.
  f32x2* myenc = (f32x2*)(enc + (size_t)blockIdx.x * 64 * KC) + tid * 2;

  // This wave scans codes [kbase, kbase+128). All codebook/ensq addresses in
  // the loop are wave-uniform -> s_load (scalar pipe); inner loop is pure
  // VALU with 4 independent fmaf chains fed from SGPRs.
  const int kbase = wave * (KC / WAVES);
  float bestd = 3.402823466e38f;
  int   besti = 0;

  for (int kk = 0; kk < KC / WAVES; kk += 4) {
    {
      const int i = kk >> 2;          // 0..31
      f32x2 zz = {0.f, 0.f};
      __builtin_nontemporal_store(zz, &myenc[i * 1024]);
      __builtin_nontemporal_store(zz, &myenc[i * 1024 + 1]);
    }
    const int kg = kbase + kk;
    const float* p = cb + (size_t)kg * DD;   // 4 consecutive code rows, 1 KB
    float s0 = 0.f, s1 = 0.f, s2 = 0.f, s3 = 0.f;
#pragma unroll
    for (int c = 0; c < DD; ++c) {
      float zc = z[c];
      s0 = fmaf(zc, p[c         ], s0);
      s1 = fmaf(zc, p[c +     DD], s1);
      s2 = fmaf(zc, p[c + 2 * DD], s2);
      s3 = fmaf(zc, p[c + 3 * DD], s3);
    }
    // mimic ref rounding: (||z||^2 + ||e||^2) - 2*(z.e), all fp32
    float d0 = (zsq + ensq_g[kg + 0]) - 2.f * s0;
    float d1 = (zsq + ensq_g[kg + 1]) - 2.f * s1;
    float d2 = (zsq + ensq_g[kg + 2]) - 2.f * s2;
    float d3 = (zsq + ensq_g[kg + 3]) - 2.f * s3;
    if (d0 < bestd) { bestd = d0; besti = kg + 0; }
    if (d1 < bestd) { bestd = d1; besti = kg + 1; }
    if (d2 < bestd) { bestd = d2; besti = kg + 2; }
    if (d3 < bestd) { bestd = d3; besti = kg + 3; }
  }

  s_val[wave][lane] = bestd;
  s_idx[wave][lane] = besti;
  __syncthreads();   // also drains (vmcnt 0) the zero-fill stores

  // cross-wave argmin reduce (first-min tie-break on lower index) + the
  // one-hot 1.0 scatter (zeros for these addresses completed at the barrier)
  if (wave == 0) {
    float bd = s_val[0][lane];
    int   bi = s_idx[0][lane];
#pragma unroll
    for (int w2 = 1; w2 < WAVES; ++w2) {
      float d  = s_val[w2][lane];
      int   i2 = s_idx[w2][lane];
      if (d < bd || (d == bd && i2 < bi)) { bd = d; bi = i2; }
    }
    s_idx[0][lane] = bi;   // broadcast final index
    atomicAdd(&hist[bi], 1);
    enc[(size_t)n * KC + bi] = 1.0f;
  }
  __syncthreads();

  // fused epilogue: q_out write + loss partial. Each wave handles 8 channels
  // for all 64 rows of the block. Reload z from global (L1/L2-hot) to avoid
  // runtime-indexing the z[] register array (scratch spill, rule #20).
  const int bif = s_idx[0][lane];
  const float* cbrow = cb + (size_t)bif * DD;
  float* qp = qout + (size_t)b * CHW + hw;
  float lacc = 0.f;
#pragma unroll
  for (int j = 0; j < DD / WAVES; ++j) {
    int c = wave * (DD / WAVES) + j;
    float v    = cbrow[c];
    float zc   = zp[(size_t)c << 10];
    float diff = v - zc;               // matches ref (quantized - ze)
    qp[(size_t)c << 10] = zc + diff;   // matches ref ze + (quantized - ze)
    lacc = fmaf(diff, diff, lacc);
  }
#pragma unroll
  for (int off = 32; off > 0; off >>= 1) lacc += __shfl_down(lacc, off, 64);
  if (lane == 0) s_loss[wave] = lacc;
  __syncthreads();
  if (tid == 0) {
    float t = 0.f;
#pragma unroll
    for (int w2 = 0; w2 < WAVES; ++w2) t += s_loss[w2];
    partials[blockIdx.x] = t;
  }
}

__global__ __launch_bounds__(1024) void vq_finalize_kernel(
    const int* __restrict__ hist, const float* __restrict__ partials,
    float* __restrict__ out_loss, float* __restrict__ out_ppl) {
  __shared__ float red[1024];
  const int t = threadIdx.x;

  // entropy term
  float p   = (float)hist[t] * (1.0f / 32768.0f);
  float ent = p * logf(p + 1e-10f);
  red[t] = ent;
  __syncthreads();
  for (int s = 512; s > 0; s >>= 1) {
    if (t < s) red[t] += red[t + s];
    __syncthreads();
  }
  float entropy = red[0];
  __syncthreads();

  // loss sum
  red[t] = (t < 512) ? partials[t] : 0.f;
  __syncthreads();
  for (int s = 512; s > 0; s >>= 1) {
    if (t < s) red[t] += red[t + s];
    __syncthreads();
  }
  if (t == 0) {
    *out_loss = 0.25f * (red[0] * (1.0f / 2097152.0f));
    *out_ppl  = expf(-entropy);
  }
}

extern "C" void kernel_launch(void* const* d_in, const int* in_sizes, int n_in,
                              void* d_out, int out_size, void* d_ws, size_t ws_size,
                              hipStream_t stream) {
  const float* z_e = (const float*)d_in[0];
  const float* cb  = (const float*)d_in[1];

  float* out  = (float*)d_out;
  float* qout = out;                       // 2097152
  float* loss = out + 2097152;
  float* ppl  = out + 2097153;
  float* enc  = out + 2097154;             // 33554432 floats

  int*   hist     = (int*)d_ws;
  float* ensq     = (float*)d_ws + 1024;
  float* partials = (float*)d_ws + 34816;

  vq_ensq_kernel<<<4, 256, 0, stream>>>(cb, ensq, hist);
  vq_argmin_kernel<<<512, 512, 0, stream>>>(z_e, cb, ensq, qout, enc, hist, partials);
  vq_finalize_kernel<<<1, 1024, 0, stream>>>(hist, partials, loss, ppl);
}

// Round 5
// 95.714 us; speedup vs baseline: 1.4040x; 1.0987x over previous
//
#include <hip/hip_runtime.h>

// VQ-VAE vector quantizer, MI355X.
// z_e: [32,64,32,32] f32, codebook: [1024,64] f32.
// d_out = q_out(2097152) | loss(1) | perplexity(1) | encodings(33554432), all f32.
//
// Pipeline (3 dispatches):
//   1. vq_ensq_kernel    : codebook squared norms + hist zero (1024 threads)
//   2. vq_argmin_kernel  : fused distances+argmin+q_out+loss+hist+encodings
//   3. vq_finalize_kernel: loss mean + perplexity
//
// ws layout (4-byte units):
//   [0,1024)       hist (int)
//   [1024,2048)    ensq (float)
//   [34816,35328)  partials (float[512])

#define NROWS 32768
#define KC    1024
#define DD    64
#define HW    1024
#define CHW   65536
#define WAVES 8           // 512 threads/block, 8-way K split (128 codes/wave)

typedef float f32x2 __attribute__((ext_vector_type(2)));

__global__ __launch_bounds__(256) void vq_ensq_kernel(const float* __restrict__ cb,
                                                      float* __restrict__ ensq,
                                                      int* __restrict__ hist) {
  int k = blockIdx.x * 256 + threadIdx.x;   // 4 blocks x 256 = exactly KC
  hist[k] = 0;
  const float* row = cb + k * DD;
  float s = 0.f;
#pragma unroll
  for (int c = 0; c < DD; ++c) s = fmaf(row[c], row[c], s);
  ensq[k] = s;
}

// waves_per_eu(4,4): grid = 512 blocks on 256 CUs = 2 blocks/CU = 4 waves/EU.
// Round-4 pathology: default heuristic targeted 8 waves/EU, squeezed arch
// VGPRs to 48 and parked z[64] in AGPRs (accvgpr_read per FMA operand).
// Pinning the occupancy target at the real value gives a 128-VGPR budget so
// z stays in arch VGPRs and the K-loop is pure v_fmac fed by s_load codebook.
__global__ __launch_bounds__(512)
__attribute__((amdgpu_waves_per_eu(4, 4)))
void vq_argmin_kernel(
    const float* __restrict__ z_e, const float* __restrict__ cb,
    const float* __restrict__ ensq_g, float* __restrict__ qout,
    float* __restrict__ enc, int* __restrict__ hist,
    float* __restrict__ partials) {
  __shared__ float s_val[WAVES][64];
  __shared__ int   s_idx[WAVES][64];
  __shared__ float s_loss[WAVES];

  const int tid  = threadIdx.x;
  const int lane = tid & 63;
  const int wave = __builtin_amdgcn_readfirstlane(tid >> 6);  // wave-uniform
  const int n    = blockIdx.x * 64 + lane;
  const int b    = n >> 10;
  const int hw   = n & (HW - 1);
  const float* zp = z_e + (size_t)b * CHW + hw;

  // this thread's z vector: 64 VGPRs, coalesced loads (lanes = consecutive hw).
  // asm pin: opaque asm result -> compiler cannot rematerialize the loads
  // inside the K-loop.
  float z[DD];
#pragma unroll
  for (int c = 0; c < DD; ++c) {
    z[c] = zp[(size_t)c << 10];
    asm volatile("" : "+v"(z[c]));
  }

  float zsq = 0.f;
#pragma unroll
  for (int c = 0; c < DD; ++c) zsq = fmaf(z[c], z[c], zsq);

  // Streaming zero-fill of this block's encodings slice (64 rows x 1024 =
  // 256 KB), interleaved with the distance loop: 16 B/thread/K-group.
  // 8-byte stores because enc base (float offset 2097154) is 8B-aligned only.
  f32x2* myenc = (f32x2*)(enc + (size_t)blockIdx.x * 64 * KC) + tid * 2;

  // This wave scans codes [kbase, kbase+128). All codebook/ensq addresses in
  // the loop are wave-uniform -> s_load (scalar pipe); inner loop is pure
  // VALU with 4 independent fmaf chains fed from SGPRs.
  const int kbase = wave * (KC / WAVES);
  float bestd = 3.402823466e38f;
  int   besti = 0;

  for (int kk = 0; kk < KC / WAVES; kk += 4) {
    {
      const int i = kk >> 2;          // 0..31
      f32x2 zz = {0.f, 0.f};
      __builtin_nontemporal_store(zz, &myenc[i * 1024]);
      __builtin_nontemporal_store(zz, &myenc[i * 1024 + 1]);
    }
    const int kg = kbase + kk;
    const float* p = cb + (size_t)kg * DD;   // 4 consecutive code rows, 1 KB
    float s0 = 0.f, s1 = 0.f, s2 = 0.f, s3 = 0.f;
#pragma unroll
    for (int c = 0; c < DD; ++c) {
      float zc = z[c];
      s0 = fmaf(zc, p[c         ], s0);
      s1 = fmaf(zc, p[c +     DD], s1);
      s2 = fmaf(zc, p[c + 2 * DD], s2);
      s3 = fmaf(zc, p[c + 3 * DD], s3);
    }
    // mimic ref rounding: (||z||^2 + ||e||^2) - 2*(z.e), all fp32
    float d0 = (zsq + ensq_g[kg + 0]) - 2.f * s0;
    float d1 = (zsq + ensq_g[kg + 1]) - 2.f * s1;
    float d2 = (zsq + ensq_g[kg + 2]) - 2.f * s2;
    float d3 = (zsq + ensq_g[kg + 3]) - 2.f * s3;
    if (d0 < bestd) { bestd = d0; besti = kg + 0; }
    if (d1 < bestd) { bestd = d1; besti = kg + 1; }
    if (d2 < bestd) { bestd = d2; besti = kg + 2; }
    if (d3 < bestd) { bestd = d3; besti = kg + 3; }
  }

  s_val[wave][lane] = bestd;
  s_idx[wave][lane] = besti;
  __syncthreads();   // also drains (vmcnt 0) the zero-fill stores

  // cross-wave argmin reduce (first-min tie-break on lower index) + the
  // one-hot 1.0 scatter (zeros for these addresses completed at the barrier)
  if (wave == 0) {
    float bd = s_val[0][lane];
    int   bi = s_idx[0][lane];
#pragma unroll
    for (int w2 = 1; w2 < WAVES; ++w2) {
      float d  = s_val[w2][lane];
      int   i2 = s_idx[w2][lane];
      if (d < bd || (d == bd && i2 < bi)) { bd = d; bi = i2; }
    }
    s_idx[0][lane] = bi;   // broadcast final index
    atomicAdd(&hist[bi], 1);
    enc[(size_t)n * KC + bi] = 1.0f;
  }
  __syncthreads();

  // fused epilogue: q_out write + loss partial. Each wave handles 8 channels
  // for all 64 rows of the block. Reload z from global (L1/L2-hot) to avoid
  // runtime-indexing the z[] register array (scratch spill, rule #20).
  const int bif = s_idx[0][lane];
  const float* cbrow = cb + (size_t)bif * DD;
  float* qp = qout + (size_t)b * CHW + hw;
  float lacc = 0.f;
#pragma unroll
  for (int j = 0; j < DD / WAVES; ++j) {
    int c = wave * (DD / WAVES) + j;
    float v    = cbrow[c];
    float zc   = zp[(size_t)c << 10];
    float diff = v - zc;               // matches ref (quantized - ze)
    qp[(size_t)c << 10] = zc + diff;   // matches ref ze + (quantized - ze)
    lacc = fmaf(diff, diff, lacc);
  }
#pragma unroll
  for (int off = 32; off > 0; off >>= 1) lacc += __shfl_down(lacc, off, 64);
  if (lane == 0) s_loss[wave] = lacc;
  __syncthreads();
  if (tid == 0) {
    float t = 0.f;
#pragma unroll
    for (int w2 = 0; w2 < WAVES; ++w2) t += s_loss[w2];
    partials[blockIdx.x] = t;
  }
}

__global__ __launch_bounds__(1024) void vq_finalize_kernel(
    const int* __restrict__ hist, const float* __restrict__ partials,
    float* __restrict__ out_loss, float* __restrict__ out_ppl) {
  __shared__ float red[1024];
  const int t = threadIdx.x;

  // entropy term
  float p   = (float)hist[t] * (1.0f / 32768.0f);
  float ent = p * logf(p + 1e-10f);
  red[t] = ent;
  __syncthreads();
  for (int s = 512; s > 0; s >>= 1) {
    if (t < s) red[t] += red[t + s];
    __syncthreads();
  }
  float entropy = red[0];
  __syncthreads();

  // loss sum
  red[t] = (t < 512) ? partials[t] : 0.f;
  __syncthreads();
  for (int s = 512; s > 0; s >>= 1) {
    if (t < s) red[t] += red[t + s];
    __syncthreads();
  }
  if (t == 0) {
    *out_loss = 0.25f * (red[0] * (1.0f / 2097152.0f));
    *out_ppl  = expf(-entropy);
  }
}

extern "C" void kernel_launch(void* const* d_in, const int* in_sizes, int n_in,
                              void* d_out, int out_size, void* d_ws, size_t ws_size,
                              hipStream_t stream) {
  const float* z_e = (const float*)d_in[0];
  const float* cb  = (const float*)d_in[1];

  float* out  = (float*)d_out;
  float* qout = out;                       // 2097152
  float* loss = out + 2097152;
  float* ppl  = out + 2097153;
  float* enc  = out + 2097154;             // 33554432 floats

  int*   hist     = (int*)d_ws;
  float* ensq     = (float*)d_ws + 1024;
  float* partials = (float*)d_ws + 34816;

  vq_ensq_kernel<<<4, 256, 0, stream>>>(cb, ensq, hist);
  vq_argmin_kernel<<<512, 512, 0, stream>>>(z_e, cb, ensq, qout, enc, hist, partials);
  vq_finalize_kernel<<<1, 1024, 0, stream>>>(hist, partials, loss, ppl);
}